// Round 1
// 630.277 us; speedup vs baseline: 1.0041x; 1.0041x over previous
//
#include <hip/hip_runtime.h>

#define IS2 0.70710678118654752440f   // np.float32(1/sqrt(2))

__device__ __forceinline__ int refl(int i, int n) {
    if (i < 0) i = -1 - i;
    if (i >= n) i = 2 * n - 1 - i;
    return i;
}

__device__ __forceinline__ float smag(float re, float im) {
    return sqrtf(re * re + im * im + 1.0e-4f) - 0.01f;
}

// ---------------------------------------------------------------------------
// fwd_j1: rowfilter(h0/h1) -> colfilter(h0/h1) -> q2c -> mag  (+ ll raw or pooled)
// MODE 0: level-1 on x:   write ll (raw, N x N) to ll_out, mags to p buffer
// MODE 1: level-2 on p:   CH==18 (pchan = o1*3+c). mags -> Z groups 13+o2*6+o1,
//         avgpool2(ll) -> Z groups 1+o1.
// Tile: 64x64 output pixels per block, halo 3.
//
// v2 (this round): the kernel was LDS-instruction-throughput bound (~600
// scalar ds_read_b32/thread). Restructured:
//  * row pass: thread computes 4 adjacent columns from 3x ds_read_b128
//    (12 b32 reads -> 3 b128), results written back as float4.
//  * col pass: thread owns ONE column x 16-row strip; loads 22+22 values
//    once into registers (conflict-free, pairable to ds_read2st64) and
//    slides the 5/7-tap windows in registers (384 reads -> 44).
//  * q2c quad combine via __shfl_xor(.,1) (DPP, VALU pipe, no LDS):
//    both parities compute smag(p - shfl(q), shfl(p) + q); evens get mA,
//    odds get mB (smag symmetric in re/im) -> branch-free.
// LDS unchanged: sx (70x72) reused as shi after the row pass; slo separate.
// 38.1 KB -> 4 blocks/CU.
// ---------------------------------------------------------------------------
template <int MODE>
__global__ __launch_bounds__(256, 4)
void fwd_j1_kernel(const float* __restrict__ in,
                   const float* __restrict__ h0,
                   const float* __restrict__ h1,
                   float* __restrict__ ll_out,
                   float* __restrict__ mag_out,
                   int CH, int N)
{
    const int img = blockIdx.z;
    const int b   = img / CH;
    const int chn = img % CH;
    const int ty0 = blockIdx.y * 64;
    const int tx0 = blockIdx.x * 64;
    const int tid = threadIdx.x;

    __shared__ __align__(16) float sx[70 * 72];   // input tile, then shi (70*64)
    __shared__ __align__(16) float slo[70 * 64];
    float* const shi = sx;   // row-filtered hi plane lives where the input was

    float f0[5], f1[7];
#pragma unroll
    for (int t = 0; t < 5; ++t) f0[t] = h0[t];
#pragma unroll
    for (int t = 0; t < 7; ++t) f1[t] = h1[t];

    const float* src = in + (size_t)img * N * N;

    // ---- load input tile with halo 3 (70x70), reflect at borders ----
    for (int e = tid; e < 70 * 70; e += 256) {
        int rr = e / 70, cc = e % 70;
        int gr = refl(ty0 - 3 + rr, N);
        int gc = refl(tx0 - 3 + cc, N);
        sx[rr * 72 + cc] = src[(size_t)gr * N + gc];
    }
    __syncthreads();

    // ---- row pass: 70 rows x 16 col-groups of 4; 3x b128 reads per group ----
    // output col jo needs sx cols jo..jo+6 (hi) / jo+1..jo+5 (lo); group g
    // covers jo = 4g..4g+3 -> window sx cols 4g..4g+9 (read 12, use 10).
    float rlo[5][4], rhi[5][4];
#pragma unroll
    for (int k = 0; k < 5; ++k) {
        int e = tid + k * 256;
        if (e < 1120) {
            int rr = e >> 4, g = e & 15;
            const float4* w4 = (const float4*)&sx[rr * 72 + 4 * g];  // 16B aligned
            float4 wa = w4[0], wb = w4[1], wc = w4[2];
            float win[12] = {wa.x, wa.y, wa.z, wa.w,
                             wb.x, wb.y, wb.z, wb.w,
                             wc.x, wc.y, wc.z, wc.w};
#pragma unroll
            for (int u = 0; u < 4; ++u) {
                float lo = 0.f, hi = 0.f;
#pragma unroll
                for (int t = 0; t < 5; ++t) lo += win[u + 1 + t] * f0[t];
#pragma unroll
                for (int t = 0; t < 7; ++t) hi += win[u + t] * f1[t];
                rlo[k][u] = lo; rhi[k][u] = hi;
            }
        }
    }
    __syncthreads();   // all reads of sx complete
#pragma unroll
    for (int k = 0; k < 5; ++k) {
        int e = tid + k * 256;
        if (e < 1120) {
            int rr = e >> 4, g = e & 15;
            *(float4*)&slo[rr * 64 + 4 * g] =
                make_float4(rlo[k][0], rlo[k][1], rlo[k][2], rlo[k][3]);
            *(float4*)&shi[rr * 64 + 4 * g] =
                make_float4(rhi[k][0], rhi[k][1], rhi[k][2], rhi[k][3]);
        }
    }
    __syncthreads();

    // ---- col pass: one column x 16-row strip per thread, sliding window ----
    const int j     = tid & 63;    // output column (lanes 0..63 -> conflict-free)
    const int rg    = tid >> 6;    // row-group 0..3 -> rows rg*16 .. rg*16+15
    const int rbase = rg * 16;

    float clo[22], chi[22];
#pragma unroll
    for (int t = 0; t < 22; ++t) {
        clo[t] = slo[(rbase + t) * 64 + j];
        chi[t] = shi[(rbase + t) * 64 + j];
    }

    const int Nh  = N >> 1;
    const int par = j & 1;
    const int qx  = (tx0 >> 1) + (j >> 1);
    const int qy0 = (ty0 >> 1) + rg * 8;
    // even lane produces mA -> orients {lh:0, hh:1, hl:2};
    // odd  lane produces mB -> orients {lh:5, hh:4, hl:3}
    const int oLH = par ? 5 : 0;
    const int oHH = par ? 4 : 1;
    const int oHL = par ? 3 : 2;

    // precomputed output bases
    float* lcol = nullptr;
    float* pLH = nullptr; float* pHH = nullptr; float* pHL = nullptr;
    float* zBase = nullptr;
    size_t zLH = 0, zHH = 0, zHL = 0, zPL = 0;
    if (MODE == 0) {
        lcol = ll_out + (size_t)img * N * N + (size_t)(ty0 + rbase) * N + tx0 + j;
        const size_t planeSz = (size_t)Nh * Nh;
        const size_t qoff = (size_t)qy0 * Nh + qx;
        pLH = mag_out + ((size_t)(b * 6 + oLH) * CH + chn) * planeSz + qoff;
        pHH = mag_out + ((size_t)(b * 6 + oHH) * CH + chn) * planeSz + qoff;
        pHL = mag_out + ((size_t)(b * 6 + oHL) * CH + chn) * planeSz + qoff;
    } else {
        const int o1 = chn / 3, c3 = chn % 3;
        zBase = mag_out + (size_t)b * 147 * 16384 + (size_t)qy0 * 128 + qx;
        zLH = (size_t)((13 + oLH * 6 + o1) * 3 + c3) * 16384;
        zHH = (size_t)((13 + oHH * 6 + o1) * 3 + c3) * 16384;
        zHL = (size_t)((13 + oHL * 6 + o1) * 3 + c3) * 16384;
        zPL = (size_t)((1 + o1) * 3 + c3) * 16384;
    }

#pragma unroll
    for (int ii = 0; ii < 8; ++ii) {
        const int i0 = 2 * ii, i1 = 2 * ii + 1;
        float ll0 = 0.f, ll1 = 0.f, lh0 = 0.f, lh1 = 0.f;
        float hl0 = 0.f, hl1 = 0.f, hh0 = 0.f, hh1 = 0.f;
#pragma unroll
        for (int t = 0; t < 5; ++t) {
            ll0 += clo[i0 + 1 + t] * f0[t]; ll1 += clo[i1 + 1 + t] * f0[t];
            hl0 += chi[i0 + 1 + t] * f0[t]; hl1 += chi[i1 + 1 + t] * f0[t];
        }
#pragma unroll
        for (int t = 0; t < 7; ++t) {
            lh0 += clo[i0 + t] * f1[t]; lh1 += clo[i1 + t] * f1[t];
            hh0 += chi[i0 + t] * f1[t]; hh1 += chi[i1 + t] * f1[t];
        }

        // q2c across the lane pair (even: a,c | odd: b,d).
        // even: re = a-d, im = b+c (mA); odd: re = b-c, im = a+d (-> mB,
        // smag symmetric in re/im). Both = smag(p - shfl(q), shfl(p) + q).
        float lhT = __shfl_xor(lh0, 1), lhB = __shfl_xor(lh1, 1);
        float hhT = __shfl_xor(hh0, 1), hhB = __shfl_xor(hh1, 1);
        float hlT = __shfl_xor(hl0, 1), hlB = __shfl_xor(hl1, 1);
        float mLH = smag(IS2 * (lh0 - lhB), IS2 * (lhT + lh1));
        float mHH = smag(IS2 * (hh0 - hhB), IS2 * (hhT + hh1));
        float mHL = smag(IS2 * (hl0 - hlB), IS2 * (hlT + hl1));

        if (MODE == 0) {
            lcol[(size_t)i0 * N] = ll0;
            lcol[(size_t)i1 * N] = ll1;
            pLH[(size_t)ii * Nh] = mLH;
            pHH[(size_t)ii * Nh] = mHH;
            pHL[(size_t)ii * Nh] = mHL;
        } else {
            float* zr = zBase + (size_t)ii * 128;
            zr[zLH] = mLH;
            zr[zHH] = mHH;
            zr[zHL] = mHL;
            float llT = __shfl_xor(ll0, 1), llB = __shfl_xor(ll1, 1);
            if (par == 0) {
                zr[zPL] = 0.25f * (ll0 + ll1 + llT + llB);
            }
        }
    }
}

// ---------------------------------------------------------------------------
// fwd_j2plus fused: rowdfilt -> coldfilt -> q2c -> mag -> Z[s1_j2], avgpool -> Z[s0]
// Input: ll (B*3, 512, 512). Output tile: 32x32 in the 256x256 "ll2" space.
// LDS reuse: sx (80x84) overwritten after the row pass with slo/shi (stride 33
// to spread banks). 26.9 KB total -> 6 blocks/CU.  (unchanged this round)
// ---------------------------------------------------------------------------
__global__ __launch_bounds__(256, 4)
void fwd_j2_kernel(const float* __restrict__ ll,
                   const float* __restrict__ h0a, const float* __restrict__ h0b,
                   const float* __restrict__ h1a, const float* __restrict__ h1b,
                   float* __restrict__ Z)
{
    const int img = blockIdx.z;            // b*3 + c
    const int b = img / 3, c = img % 3;
    const int r0 = blockIdx.y * 32;        // origin in 256-space rows
    const int c0 = blockIdx.x * 32;        // origin in 256-space cols
    const int tid = threadIdx.x;

    __shared__ float sx[80 * 84];          // input tile, then slo/shi (stride 33)
    float* const sloP = sx;                // [80][33] flat, max 2638
    float* const shiP = sx + 2688;         // [80][33] flat, max 2688+2638=5326 < 6720

    float fa0[10], fb0[10], fa1[10], fb1[10];
#pragma unroll
    for (int t = 0; t < 10; ++t) {
        fa0[t] = h0a[t]; fb0[t] = h0b[t];
        fa1[t] = h1a[t]; fb1[t] = h1b[t];
    }

    const float* src = ll + (size_t)img * 512 * 512;

    // ---- load 80x80 x-tile (rows/cols 2r0-8 .. 2r0+71), reflect ----
    for (int e = tid; e < 80 * 80; e += 256) {
        int rr = e / 80, cc = e % 80;
        int gr = refl(2 * r0 - 8 + rr, 512);
        int gc = refl(2 * c0 - 8 + cc, 512);
        sx[rr * 84 + cc] = src[(size_t)gr * 512 + gc];
    }
    __syncthreads();

    // ---- row pass (rowdfilt) into registers ----
    const int jj  = tid & 31;          // tile col (fixed per thread)
    const int odd = jj & 1;
    const int base = 2 * (jj & ~1);    // sx col of x index 4j-8 (+8 halo)
    float hlo[10], hhi[10];
#pragma unroll
    for (int t = 0; t < 10; ++t) {
        hlo[t] = odd ? fa0[t] : fb0[t];   // odd col -> h0a, even -> h0b
        hhi[t] = odd ? fb1[t] : fa1[t];   // odd col -> h1b, even -> h1a
    }
    const int offlo = base + odd;
    const int offhi = base + 1 - odd;
    float rlo[10], rhi[10];
#pragma unroll
    for (int k = 0; k < 10; ++k) {
        int rr = (tid >> 5) + 8 * k;
        const float* row = &sx[rr * 84];
        float lo = 0.f, hi = 0.f;
#pragma unroll
        for (int t = 0; t < 10; ++t) {
            lo += row[offlo + 2 * t] * hlo[t];
            hi += row[offhi + 2 * t] * hhi[t];
        }
        rlo[k] = lo; rhi[k] = hi;
    }
    __syncthreads();   // all reads of sx complete
#pragma unroll
    for (int k = 0; k < 10; ++k) {
        int rr = (tid >> 5) + 8 * k;
        sloP[rr * 33 + jj] = rlo[k];
        shiP[rr * 33 + jj] = rhi[k];
    }
    __syncthreads();

    // ---- col pass (coldfilt) : one quad per thread (16x16 quads) ----
    const int qi = tid >> 4, qj = tid & 15;
    float ll2[2][2], lh4[2][2], hl4[2][2], hh4[2][2];
#pragma unroll
    for (int dj = 0; dj < 2; ++dj) {
        const int col = 2 * qj + dj;
        const int rb  = 4 * qi;
        float vll0 = 0.f, vll1 = 0.f, vlh0 = 0.f, vlh1 = 0.f;
        float vhl0 = 0.f, vhl1 = 0.f, vhh0 = 0.f, vhh1 = 0.f;
#pragma unroll
        for (int t = 0; t < 10; ++t) {
            float e0 = sloP[(rb + 2 * t) * 33 + col];
            float e1 = sloP[(rb + 2 * t + 1) * 33 + col];
            float g0 = shiP[(rb + 2 * t) * 33 + col];
            float g1 = shiP[(rb + 2 * t + 1) * 33 + col];
            vll0 += e0 * fb0[t];   // row 2i   : h0b
            vll1 += e1 * fa0[t];   // row 2i+1 : h0a
            vlh0 += e1 * fa1[t];   // row 2i   : h1a (highpass swaps)
            vlh1 += e0 * fb1[t];   // row 2i+1 : h1b
            vhl0 += g0 * fb0[t];
            vhl1 += g1 * fa0[t];
            vhh0 += g1 * fa1[t];
            vhh1 += g0 * fb1[t];
        }
        ll2[0][dj] = vll0; ll2[1][dj] = vll1;
        lh4[0][dj] = vlh0; lh4[1][dj] = vlh1;
        hl4[0][dj] = vhl0; hl4[1][dj] = vhl1;
        hh4[0][dj] = vhh0; hh4[1][dj] = vhh1;
    }

    const int qy = (r0 >> 1) + qi;
    const int qx = (c0 >> 1) + qj;
    float* Zb = Z + (size_t)b * 147 * 16384 + (size_t)qy * 128 + qx;

    // s0 = avgpool2(ll2), group 0
    Zb[(size_t)c * 16384] =
        0.25f * (ll2[0][0] + ll2[0][1] + ll2[1][0] + ll2[1][1]);

    // s1_j2: groups 7+o
    {
        float a, bq, cq, d;
        float m[6];
        a = lh4[0][0] * IS2; bq = lh4[0][1] * IS2; cq = lh4[1][0] * IS2; d = lh4[1][1] * IS2;
        m[0] = smag(a - d, bq + cq); m[5] = smag(a + d, bq - cq);
        a = hh4[0][0] * IS2; bq = hh4[0][1] * IS2; cq = hh4[1][0] * IS2; d = hh4[1][1] * IS2;
        m[1] = smag(a - d, bq + cq); m[4] = smag(a + d, bq - cq);
        a = hl4[0][0] * IS2; bq = hl4[0][1] * IS2; cq = hl4[1][0] * IS2; d = hl4[1][1] * IS2;
        m[2] = smag(a - d, bq + cq); m[3] = smag(a + d, bq - cq);
#pragma unroll
        for (int o = 0; o < 6; ++o) {
            Zb[(size_t)((7 + o) * 3 + c) * 16384] = m[o];
        }
    }
}

extern "C" void kernel_launch(void* const* d_in, const int* in_sizes, int n_in,
                              void* d_out, int out_size, void* d_ws, size_t ws_size,
                              hipStream_t stream)
{
    const float* x   = (const float*)d_in[0];
    const float* h0o = (const float*)d_in[1];
    const float* h1o = (const float*)d_in[2];
    const float* h0a = (const float*)d_in[3];
    const float* h0b = (const float*)d_in[4];
    const float* h1a = (const float*)d_in[5];
    const float* h1b = (const float*)d_in[6];
    float* Z = (float*)d_out;

    float* ws_ll = (float*)d_ws;                          // (32,3,512,512)
    float* ws_p  = ws_ll + (size_t)32 * 3 * 512 * 512;    // (32,18,256,256)

    dim3 blk(256);
    // level 1 on x -> ll + p
    fwd_j1_kernel<0><<<dim3(8, 8, 96), blk, 0, stream>>>(x, h0o, h1o, ws_ll, ws_p, 3, 512);
    // level 2 (decimating) on ll -> Z[s0], Z[s1_j2]
    fwd_j2_kernel<<<dim3(8, 8, 96), blk, 0, stream>>>(ws_ll, h0a, h0b, h1a, h1b, Z);
    // level-1 transform on p -> Z[s1_j1 pooled], Z[s2]
    fwd_j1_kernel<1><<<dim3(4, 4, 576), blk, 0, stream>>>(ws_p, h0o, h1o, nullptr, Z, 18, 256);
}

// Round 2
// 590.295 us; speedup vs baseline: 1.0721x; 1.0677x over previous
//
#include <hip/hip_runtime.h>

#define IS2 0.70710678118654752440f   // np.float32(1/sqrt(2))

__device__ __forceinline__ int refl(int i, int n) {
    if (i < 0) i = -1 - i;
    if (i >= n) i = 2 * n - 1 - i;
    return i;
}

__device__ __forceinline__ float smag(float re, float im) {
    return sqrtf(re * re + im * im + 1.0e-4f) - 0.01f;
}

// ---------------------------------------------------------------------------
// j1 tile (device fn): rowfilter(h0/h1) -> colfilter(h0/h1) -> q2c -> mag
// MODE 0: level-1 on x (N=512): ll raw -> ll_out, mags -> p buffer
// MODE 1: level-2 on p (N=256, CH=18): mags -> Z groups 13+o2*6+o1,
//         avgpool2(ll) -> Z groups 1+o1.
// smem layout: sx = smem[0..5039] (70x72, reused as shi 70x64 flat),
//              slo = smem[5040..9519] (70x64). 38.1 KB -> 4 blocks/CU.
// Internals identical to round-1 v2 (register sliding-window col pass,
// b128 row pass, shfl_xor q2c).
// ---------------------------------------------------------------------------
template <int MODE>
__device__ __forceinline__
void j1_tile(float* __restrict__ smem,
             const float* __restrict__ in,
             const float* __restrict__ h0,
             const float* __restrict__ h1,
             float* __restrict__ ll_out,
             float* __restrict__ mag_out,
             int CH, int N, int img, int ty0, int tx0)
{
    const int b   = img / CH;
    const int chn = img % CH;
    const int tid = threadIdx.x;

    float* const sx  = smem;          // 70*72
    float* const slo = smem + 5040;   // 70*64
    float* const shi = sx;            // row-filtered hi plane overlays input

    float f0[5], f1[7];
#pragma unroll
    for (int t = 0; t < 5; ++t) f0[t] = h0[t];
#pragma unroll
    for (int t = 0; t < 7; ++t) f1[t] = h1[t];

    const float* src = in + (size_t)img * N * N;

    // ---- load input tile with halo 3 (70x70), reflect at borders ----
    for (int e = tid; e < 70 * 70; e += 256) {
        int rr = e / 70, cc = e % 70;
        int gr = refl(ty0 - 3 + rr, N);
        int gc = refl(tx0 - 3 + cc, N);
        sx[rr * 72 + cc] = src[(size_t)gr * N + gc];
    }
    __syncthreads();

    // ---- row pass: 70 rows x 16 col-groups of 4; 3x b128 reads per group ----
    float rlo[5][4], rhi[5][4];
#pragma unroll
    for (int k = 0; k < 5; ++k) {
        int e = tid + k * 256;
        if (e < 1120) {
            int rr = e >> 4, g = e & 15;
            const float4* w4 = (const float4*)&sx[rr * 72 + 4 * g];  // 16B aligned
            float4 wa = w4[0], wb = w4[1], wc = w4[2];
            float win[12] = {wa.x, wa.y, wa.z, wa.w,
                             wb.x, wb.y, wb.z, wb.w,
                             wc.x, wc.y, wc.z, wc.w};
#pragma unroll
            for (int u = 0; u < 4; ++u) {
                float lo = 0.f, hi = 0.f;
#pragma unroll
                for (int t = 0; t < 5; ++t) lo += win[u + 1 + t] * f0[t];
#pragma unroll
                for (int t = 0; t < 7; ++t) hi += win[u + t] * f1[t];
                rlo[k][u] = lo; rhi[k][u] = hi;
            }
        }
    }
    __syncthreads();   // all reads of sx complete
#pragma unroll
    for (int k = 0; k < 5; ++k) {
        int e = tid + k * 256;
        if (e < 1120) {
            int rr = e >> 4, g = e & 15;
            *(float4*)&slo[rr * 64 + 4 * g] =
                make_float4(rlo[k][0], rlo[k][1], rlo[k][2], rlo[k][3]);
            *(float4*)&shi[rr * 64 + 4 * g] =
                make_float4(rhi[k][0], rhi[k][1], rhi[k][2], rhi[k][3]);
        }
    }
    __syncthreads();

    // ---- col pass: one column x 16-row strip per thread, sliding window ----
    const int j     = tid & 63;    // output column
    const int rg    = tid >> 6;    // row-group 0..3
    const int rbase = rg * 16;

    float clo[22], chi[22];
#pragma unroll
    for (int t = 0; t < 22; ++t) {
        clo[t] = slo[(rbase + t) * 64 + j];
        chi[t] = shi[(rbase + t) * 64 + j];
    }

    const int Nh  = N >> 1;
    const int par = j & 1;
    const int qx  = (tx0 >> 1) + (j >> 1);
    const int qy0 = (ty0 >> 1) + rg * 8;
    const int oLH = par ? 5 : 0;
    const int oHH = par ? 4 : 1;
    const int oHL = par ? 3 : 2;

    float* lcol = nullptr;
    float* pLH = nullptr; float* pHH = nullptr; float* pHL = nullptr;
    float* zBase = nullptr;
    size_t zLH = 0, zHH = 0, zHL = 0, zPL = 0;
    if (MODE == 0) {
        lcol = ll_out + (size_t)img * N * N + (size_t)(ty0 + rbase) * N + tx0 + j;
        const size_t planeSz = (size_t)Nh * Nh;
        const size_t qoff = (size_t)qy0 * Nh + qx;
        pLH = mag_out + ((size_t)(b * 6 + oLH) * CH + chn) * planeSz + qoff;
        pHH = mag_out + ((size_t)(b * 6 + oHH) * CH + chn) * planeSz + qoff;
        pHL = mag_out + ((size_t)(b * 6 + oHL) * CH + chn) * planeSz + qoff;
    } else {
        const int o1 = chn / 3, c3 = chn % 3;
        zBase = mag_out + (size_t)b * 147 * 16384 + (size_t)qy0 * 128 + qx;
        zLH = (size_t)((13 + oLH * 6 + o1) * 3 + c3) * 16384;
        zHH = (size_t)((13 + oHH * 6 + o1) * 3 + c3) * 16384;
        zHL = (size_t)((13 + oHL * 6 + o1) * 3 + c3) * 16384;
        zPL = (size_t)((1 + o1) * 3 + c3) * 16384;
    }

#pragma unroll
    for (int ii = 0; ii < 8; ++ii) {
        const int i0 = 2 * ii, i1 = 2 * ii + 1;
        float ll0 = 0.f, ll1 = 0.f, lh0 = 0.f, lh1 = 0.f;
        float hl0 = 0.f, hl1 = 0.f, hh0 = 0.f, hh1 = 0.f;
#pragma unroll
        for (int t = 0; t < 5; ++t) {
            ll0 += clo[i0 + 1 + t] * f0[t]; ll1 += clo[i1 + 1 + t] * f0[t];
            hl0 += chi[i0 + 1 + t] * f0[t]; hl1 += chi[i1 + 1 + t] * f0[t];
        }
#pragma unroll
        for (int t = 0; t < 7; ++t) {
            lh0 += clo[i0 + t] * f1[t]; lh1 += clo[i1 + t] * f1[t];
            hh0 += chi[i0 + t] * f1[t]; hh1 += chi[i1 + t] * f1[t];
        }

        // q2c across the lane pair (even: a,c | odd: b,d); smag symmetric.
        float lhT = __shfl_xor(lh0, 1), lhB = __shfl_xor(lh1, 1);
        float hhT = __shfl_xor(hh0, 1), hhB = __shfl_xor(hh1, 1);
        float hlT = __shfl_xor(hl0, 1), hlB = __shfl_xor(hl1, 1);
        float mLH = smag(IS2 * (lh0 - lhB), IS2 * (lhT + lh1));
        float mHH = smag(IS2 * (hh0 - hhB), IS2 * (hhT + hh1));
        float mHL = smag(IS2 * (hl0 - hlB), IS2 * (hlT + hl1));

        if (MODE == 0) {
            lcol[(size_t)i0 * N] = ll0;
            lcol[(size_t)i1 * N] = ll1;
            pLH[(size_t)ii * Nh] = mLH;
            pHH[(size_t)ii * Nh] = mHH;
            pHL[(size_t)ii * Nh] = mHL;
        } else {
            float* zr = zBase + (size_t)ii * 128;
            zr[zLH] = mLH;
            zr[zHH] = mHH;
            zr[zHL] = mHL;
            float llT = __shfl_xor(ll0, 1), llB = __shfl_xor(ll1, 1);
            if (par == 0) {
                zr[zPL] = 0.25f * (ll0 + ll1 + llT + llB);
            }
        }
    }
}

// ---------------------------------------------------------------------------
// j2 tile (device fn): rowdfilt -> coldfilt -> q2c -> mag -> Z[s1_j2],
// avgpool -> Z[s0]. smem usage: 80*84 = 6720 floats (fits in the 9520 block).
// Internals identical to previous rounds.
// ---------------------------------------------------------------------------
__device__ __forceinline__
void j2_tile(float* __restrict__ smem,
             const float* __restrict__ ll,
             const float* __restrict__ h0a, const float* __restrict__ h0b,
             const float* __restrict__ h1a, const float* __restrict__ h1b,
             float* __restrict__ Z, int img, int r0, int c0)
{
    const int b = img / 3, c = img % 3;
    const int tid = threadIdx.x;

    float* const sx   = smem;          // 80*84, then slo/shi (stride 33)
    float* const sloP = sx;            // [80][33] flat
    float* const shiP = sx + 2688;

    float fa0[10], fb0[10], fa1[10], fb1[10];
#pragma unroll
    for (int t = 0; t < 10; ++t) {
        fa0[t] = h0a[t]; fb0[t] = h0b[t];
        fa1[t] = h1a[t]; fb1[t] = h1b[t];
    }

    const float* src = ll + (size_t)img * 512 * 512;

    // ---- load 80x80 x-tile (rows/cols 2r0-8 .. 2r0+71), reflect ----
    for (int e = tid; e < 80 * 80; e += 256) {
        int rr = e / 80, cc = e % 80;
        int gr = refl(2 * r0 - 8 + rr, 512);
        int gc = refl(2 * c0 - 8 + cc, 512);
        sx[rr * 84 + cc] = src[(size_t)gr * 512 + gc];
    }
    __syncthreads();

    // ---- row pass (rowdfilt) into registers ----
    const int jj  = tid & 31;
    const int odd = jj & 1;
    const int base = 2 * (jj & ~1);
    float hlo[10], hhi[10];
#pragma unroll
    for (int t = 0; t < 10; ++t) {
        hlo[t] = odd ? fa0[t] : fb0[t];
        hhi[t] = odd ? fb1[t] : fa1[t];
    }
    const int offlo = base + odd;
    const int offhi = base + 1 - odd;
    float rlo[10], rhi[10];
#pragma unroll
    for (int k = 0; k < 10; ++k) {
        int rr = (tid >> 5) + 8 * k;
        const float* row = &sx[rr * 84];
        float lo = 0.f, hi = 0.f;
#pragma unroll
        for (int t = 0; t < 10; ++t) {
            lo += row[offlo + 2 * t] * hlo[t];
            hi += row[offhi + 2 * t] * hhi[t];
        }
        rlo[k] = lo; rhi[k] = hi;
    }
    __syncthreads();
#pragma unroll
    for (int k = 0; k < 10; ++k) {
        int rr = (tid >> 5) + 8 * k;
        sloP[rr * 33 + jj] = rlo[k];
        shiP[rr * 33 + jj] = rhi[k];
    }
    __syncthreads();

    // ---- col pass (coldfilt) : one quad per thread (16x16 quads) ----
    const int qi = tid >> 4, qj = tid & 15;
    float ll2[2][2], lh4[2][2], hl4[2][2], hh4[2][2];
#pragma unroll
    for (int dj = 0; dj < 2; ++dj) {
        const int col = 2 * qj + dj;
        const int rb  = 4 * qi;
        float vll0 = 0.f, vll1 = 0.f, vlh0 = 0.f, vlh1 = 0.f;
        float vhl0 = 0.f, vhl1 = 0.f, vhh0 = 0.f, vhh1 = 0.f;
#pragma unroll
        for (int t = 0; t < 10; ++t) {
            float e0 = sloP[(rb + 2 * t) * 33 + col];
            float e1 = sloP[(rb + 2 * t + 1) * 33 + col];
            float g0 = shiP[(rb + 2 * t) * 33 + col];
            float g1 = shiP[(rb + 2 * t + 1) * 33 + col];
            vll0 += e0 * fb0[t];
            vll1 += e1 * fa0[t];
            vlh0 += e1 * fa1[t];
            vlh1 += e0 * fb1[t];
            vhl0 += g0 * fb0[t];
            vhl1 += g1 * fa0[t];
            vhh0 += g1 * fa1[t];
            vhh1 += g0 * fb1[t];
        }
        ll2[0][dj] = vll0; ll2[1][dj] = vll1;
        lh4[0][dj] = vlh0; lh4[1][dj] = vlh1;
        hl4[0][dj] = vhl0; hl4[1][dj] = vhl1;
        hh4[0][dj] = vhh0; hh4[1][dj] = vhh1;
    }

    const int qy = (r0 >> 1) + qi;
    const int qx = (c0 >> 1) + qj;
    float* Zb = Z + (size_t)b * 147 * 16384 + (size_t)qy * 128 + qx;

    Zb[(size_t)c * 16384] =
        0.25f * (ll2[0][0] + ll2[0][1] + ll2[1][0] + ll2[1][1]);

    {
        float a, bq, cq, d;
        float m[6];
        a = lh4[0][0] * IS2; bq = lh4[0][1] * IS2; cq = lh4[1][0] * IS2; d = lh4[1][1] * IS2;
        m[0] = smag(a - d, bq + cq); m[5] = smag(a + d, bq - cq);
        a = hh4[0][0] * IS2; bq = hh4[0][1] * IS2; cq = hh4[1][0] * IS2; d = hh4[1][1] * IS2;
        m[1] = smag(a - d, bq + cq); m[4] = smag(a + d, bq - cq);
        a = hl4[0][0] * IS2; bq = hl4[0][1] * IS2; cq = hl4[1][0] * IS2; d = hl4[1][1] * IS2;
        m[2] = smag(a - d, bq + cq); m[3] = smag(a + d, bq - cq);
#pragma unroll
        for (int o = 0; o < 6; ++o) {
            Zb[(size_t)((7 + o) * 3 + c) * 16384] = m[o];
        }
    }
}

// ---------------------------------------------------------------------------
// Kernel A: level-1 j1 on x -> ll + p  (identical structure to round 1)
// ---------------------------------------------------------------------------
__global__ __launch_bounds__(256, 4)
void k_j1_l1(const float* __restrict__ x,
             const float* __restrict__ h0o, const float* __restrict__ h1o,
             float* __restrict__ ll, float* __restrict__ p)
{
    __shared__ __align__(16) float smem[9520];
    j1_tile<0>(smem, x, h0o, h1o, ll, p, 3, 512,
               blockIdx.z, blockIdx.y * 64, blockIdx.x * 64);
}

// ---------------------------------------------------------------------------
// Kernel B: fused phase 2+3. j2 (6144 tiles) and j1-mode1 (9216 tiles) are
// both consumers of kernel A's outputs and independent of each other, so one
// dispatch runs both: blocks [0,6144) do j2 tiles, [6144,15360) do j1<1>
// tiles. Removes a launch gap and lets the j1<1> blocks backfill CUs during
// j2's tail. Also makes the combined dispatch big enough to surface in the
// rocprof top-5 with real counters (attribution experiment).
// ---------------------------------------------------------------------------
__global__ __launch_bounds__(256, 4)
void k_p23(const float* __restrict__ ll, const float* __restrict__ p,
           const float* __restrict__ h0o, const float* __restrict__ h1o,
           const float* __restrict__ h0a, const float* __restrict__ h0b,
           const float* __restrict__ h1a, const float* __restrict__ h1b,
           float* __restrict__ Z)
{
    __shared__ __align__(16) float smem[9520];
    const int B = blockIdx.x;
    if (B < 6144) {
        const int img = B >> 6, rem = B & 63;
        j2_tile(smem, ll, h0a, h0b, h1a, h1b, Z,
                img, ((rem >> 3) & 7) * 32, (rem & 7) * 32);
    } else {
        const int T = B - 6144;
        const int img = T >> 4, rem = T & 15;
        j1_tile<1>(smem, p, h0o, h1o, nullptr, Z, 18, 256,
                   img, ((rem >> 2) & 3) * 64, (rem & 3) * 64);
    }
}

extern "C" void kernel_launch(void* const* d_in, const int* in_sizes, int n_in,
                              void* d_out, int out_size, void* d_ws, size_t ws_size,
                              hipStream_t stream)
{
    const float* x   = (const float*)d_in[0];
    const float* h0o = (const float*)d_in[1];
    const float* h1o = (const float*)d_in[2];
    const float* h0a = (const float*)d_in[3];
    const float* h0b = (const float*)d_in[4];
    const float* h1a = (const float*)d_in[5];
    const float* h1b = (const float*)d_in[6];
    float* Z = (float*)d_out;

    float* ws_ll = (float*)d_ws;                          // (32,3,512,512)
    float* ws_p  = ws_ll + (size_t)32 * 3 * 512 * 512;    // (32,18,256,256)

    dim3 blk(256);
    // phase 1: level-1 j1 on x -> ll + p
    k_j1_l1<<<dim3(8, 8, 96), blk, 0, stream>>>(x, h0o, h1o, ws_ll, ws_p);
    // phases 2+3 fused: j2 on ll -> Z[s0,s1_j2]; j1<1> on p -> Z[s1_j1,s2]
    k_p23<<<dim3(15360), blk, 0, stream>>>(ws_ll, ws_p, h0o, h1o,
                                           h0a, h0b, h1a, h1b, Z);
}

// Round 3
// 562.076 us; speedup vs baseline: 1.1259x; 1.0502x over previous
//
#include <hip/hip_runtime.h>

#define IS2 0.70710678118654752440f   // np.float32(1/sqrt(2))

__device__ __forceinline__ int refl(int i, int n) {
    if (i < 0) i = -1 - i;
    if (i >= n) i = 2 * n - 1 - i;
    return i;
}

__device__ __forceinline__ float smag(float re, float im) {
    return sqrtf(re * re + im * im + 1.0e-4f) - 0.01f;
}

// ---------------------------------------------------------------------------
// j1 tile: rowfilter(h0/h1) -> colfilter(h0/h1) -> q2c -> mag
// MODE 0: level-1 on x (N=512, CH=3): ll raw -> ll_out, mags -> p buffer
// MODE 1: level-2 on p (N=256, CH=18): mags -> Z groups 13+o2*6+o1 (NT),
//         avgpool2(ll) -> Z groups 1+o1 (NT).
// v3: sx col c <-> global col tx0-4+c (shifted 1 vs v2) so interior blocks
// load 18 aligned float4 per row (no refl, no div-by-70). Border blocks keep
// the scalar reflect path. N/CH are template constants.
// smem: sx 70x72 (reused as shi 70x64 flat), slo 70x64. 38.1 KB.
// ---------------------------------------------------------------------------
template <int MODE, int N, int CH>
__device__ __forceinline__
void j1_tile(float* __restrict__ smem,
             const float* __restrict__ in,
             const float* __restrict__ h0,
             const float* __restrict__ h1,
             float* __restrict__ ll_out,
             float* __restrict__ mag_out,
             int img, int ty0, int tx0)
{
    const int b   = img / CH;
    const int chn = img % CH;
    const int tid = threadIdx.x;

    float* const sx  = smem;          // 70*72
    float* const slo = smem + 5040;   // 70*64
    float* const shi = sx;            // row-filtered hi plane overlays input

    float f0[5], f1[7];
#pragma unroll
    for (int t = 0; t < 5; ++t) f0[t] = h0[t];
#pragma unroll
    for (int t = 0; t < 7; ++t) f1[t] = h1[t];

    const float* src = in + (size_t)img * N * N;

    // ---- load input tile: rows ty0-3..ty0+66, cols tx0-4..tx0+67 ----
    const bool interior = (ty0 >= 3) && (ty0 + 66 <= N - 1) &&
                          (tx0 >= 4) && (tx0 + 67 <= N - 1);
    if (interior) {
        const float* bp = src + (size_t)(ty0 - 3) * N + (tx0 - 4);
        for (int e = tid; e < 70 * 18; e += 256) {
            int rr = e / 18, g = e - rr * 18;
            *(float4*)&sx[rr * 72 + 4 * g] =
                *(const float4*)(bp + (size_t)rr * N + 4 * g);
        }
    } else {
        for (int e = tid; e < 70 * 72; e += 256) {
            int rr = e / 72, cc = e - rr * 72;
            int gr = refl(ty0 - 3 + rr, N);
            int gc = refl(tx0 - 4 + cc, N);
            sx[rr * 72 + cc] = src[(size_t)gr * N + gc];
        }
    }
    __syncthreads();

    // ---- row pass: 70 rows x 16 col-groups of 4; 3x b128 reads per group ----
    // output col jo=4g+u (global tx0+jo): lo taps sx cols jo+2..jo+6,
    // hi taps jo+1..jo+7 -> window sx cols 4g..4g+11.
    float rlo[5][4], rhi[5][4];
#pragma unroll
    for (int k = 0; k < 5; ++k) {
        int e = tid + k * 256;
        if (e < 1120) {
            int rr = e >> 4, g = e & 15;
            const float4* w4 = (const float4*)&sx[rr * 72 + 4 * g];  // 16B aligned
            float4 wa = w4[0], wb = w4[1], wc = w4[2];
            float win[12] = {wa.x, wa.y, wa.z, wa.w,
                             wb.x, wb.y, wb.z, wb.w,
                             wc.x, wc.y, wc.z, wc.w};
#pragma unroll
            for (int u = 0; u < 4; ++u) {
                float lo = 0.f, hi = 0.f;
#pragma unroll
                for (int t = 0; t < 5; ++t) lo += win[u + 2 + t] * f0[t];
#pragma unroll
                for (int t = 0; t < 7; ++t) hi += win[u + 1 + t] * f1[t];
                rlo[k][u] = lo; rhi[k][u] = hi;
            }
        }
    }
    __syncthreads();   // all reads of sx complete
#pragma unroll
    for (int k = 0; k < 5; ++k) {
        int e = tid + k * 256;
        if (e < 1120) {
            int rr = e >> 4, g = e & 15;
            *(float4*)&slo[rr * 64 + 4 * g] =
                make_float4(rlo[k][0], rlo[k][1], rlo[k][2], rlo[k][3]);
            *(float4*)&shi[rr * 64 + 4 * g] =
                make_float4(rhi[k][0], rhi[k][1], rhi[k][2], rhi[k][3]);
        }
    }
    __syncthreads();

    // ---- col pass: one column x 16-row strip per thread, sliding window ----
    const int j     = tid & 63;    // output column
    const int rg    = tid >> 6;    // row-group 0..3
    const int rbase = rg * 16;

    float clo[22], chi[22];
#pragma unroll
    for (int t = 0; t < 22; ++t) {
        clo[t] = slo[(rbase + t) * 64 + j];
        chi[t] = shi[(rbase + t) * 64 + j];
    }

    const int Nh  = N >> 1;
    const int par = j & 1;
    const int qx  = (tx0 >> 1) + (j >> 1);
    const int qy0 = (ty0 >> 1) + rg * 8;
    const int oLH = par ? 5 : 0;
    const int oHH = par ? 4 : 1;
    const int oHL = par ? 3 : 2;

    float* lcol = nullptr;
    float* pLH = nullptr; float* pHH = nullptr; float* pHL = nullptr;
    float* zLH = nullptr; float* zHH = nullptr; float* zHL = nullptr;
    float* zPL = nullptr;
    if (MODE == 0) {
        lcol = ll_out + (size_t)img * N * N + (size_t)(ty0 + rbase) * N + tx0 + j;
        const size_t planeSz = (size_t)Nh * Nh;
        const size_t qoff = (size_t)qy0 * Nh + qx;
        pLH = mag_out + ((size_t)(b * 6 + oLH) * CH + chn) * planeSz + qoff;
        pHH = mag_out + ((size_t)(b * 6 + oHH) * CH + chn) * planeSz + qoff;
        pHL = mag_out + ((size_t)(b * 6 + oHL) * CH + chn) * planeSz + qoff;
    } else {
        const int o1 = chn / 3, c3 = chn % 3;
        float* zBase = mag_out + (size_t)b * 147 * 16384 + (size_t)qy0 * 128 + qx;
        zLH = zBase + (size_t)((13 + oLH * 6 + o1) * 3 + c3) * 16384;
        zHH = zBase + (size_t)((13 + oHH * 6 + o1) * 3 + c3) * 16384;
        zHL = zBase + (size_t)((13 + oHL * 6 + o1) * 3 + c3) * 16384;
        zPL = zBase + (size_t)((1 + o1) * 3 + c3) * 16384;
    }

#pragma unroll
    for (int ii = 0; ii < 8; ++ii) {
        const int i0 = 2 * ii, i1 = 2 * ii + 1;
        float ll0 = 0.f, ll1 = 0.f, lh0 = 0.f, lh1 = 0.f;
        float hl0 = 0.f, hl1 = 0.f, hh0 = 0.f, hh1 = 0.f;
#pragma unroll
        for (int t = 0; t < 5; ++t) {
            ll0 += clo[i0 + 1 + t] * f0[t]; ll1 += clo[i1 + 1 + t] * f0[t];
            hl0 += chi[i0 + 1 + t] * f0[t]; hl1 += chi[i1 + 1 + t] * f0[t];
        }
#pragma unroll
        for (int t = 0; t < 7; ++t) {
            lh0 += clo[i0 + t] * f1[t]; lh1 += clo[i1 + t] * f1[t];
            hh0 += chi[i0 + t] * f1[t]; hh1 += chi[i1 + t] * f1[t];
        }

        // q2c across the lane pair (even: a,c | odd: b,d); smag symmetric.
        float lhT = __shfl_xor(lh0, 1), lhB = __shfl_xor(lh1, 1);
        float hhT = __shfl_xor(hh0, 1), hhB = __shfl_xor(hh1, 1);
        float hlT = __shfl_xor(hl0, 1), hlB = __shfl_xor(hl1, 1);
        float mLH = smag(IS2 * (lh0 - lhB), IS2 * (lhT + lh1));
        float mHH = smag(IS2 * (hh0 - hhB), IS2 * (hhT + hh1));
        float mHL = smag(IS2 * (hl0 - hlB), IS2 * (hlT + hl1));

        if (MODE == 0) {
            lcol[(size_t)i0 * N] = ll0;
            lcol[(size_t)i1 * N] = ll1;
            pLH[ii * Nh] = mLH;
            pHH[ii * Nh] = mHH;
            pHL[ii * Nh] = mHL;
        } else {
            __builtin_nontemporal_store(mLH, zLH + ii * 128);
            __builtin_nontemporal_store(mHH, zHH + ii * 128);
            __builtin_nontemporal_store(mHL, zHL + ii * 128);
            float llT = __shfl_xor(ll0, 1), llB = __shfl_xor(ll1, 1);
            if (par == 0) {
                __builtin_nontemporal_store(
                    0.25f * (ll0 + ll1 + llT + llB), zPL + ii * 128);
            }
        }
    }
}

// ---------------------------------------------------------------------------
// j2 tile: rowdfilt -> coldfilt -> q2c -> mag -> Z[s1_j2] (NT), avgpool -> Z[s0] (NT)
// v3: vectorized interior tile load (20 aligned float4/row); col pass rewritten
// as column-sliding-window (48 conflict-free LDS reads vs 80 4-way-conflicted)
// with q2c via shfl_xor on the column-pair lanes.
// smem: sx 80x84, then sloP/shiP (stride 33). 26.9 KB.
// ---------------------------------------------------------------------------
__device__ __forceinline__
void j2_tile(float* __restrict__ smem,
             const float* __restrict__ ll,
             const float* __restrict__ h0a, const float* __restrict__ h0b,
             const float* __restrict__ h1a, const float* __restrict__ h1b,
             float* __restrict__ Z, int img, int r0, int c0)
{
    const int b = img / 3, c = img % 3;
    const int tid = threadIdx.x;

    float* const sx   = smem;          // 80*84, then slo/shi (stride 33)
    float* const sloP = sx;            // [80][33] flat
    float* const shiP = sx + 2688;

    float fa0[10], fb0[10], fa1[10], fb1[10];
#pragma unroll
    for (int t = 0; t < 10; ++t) {
        fa0[t] = h0a[t]; fb0[t] = h0b[t];
        fa1[t] = h1a[t]; fb1[t] = h1b[t];
    }

    const float* src = ll + (size_t)img * 512 * 512;
    const int gy0 = 2 * r0 - 8, gx0 = 2 * c0 - 8;

    // ---- load 80x80 x-tile (rows/cols gy0..gy0+79), reflect at borders ----
    const bool interior = (gy0 >= 0) && (gy0 + 79 <= 511) &&
                          (gx0 >= 0) && (gx0 + 79 <= 511);
    if (interior) {
        const float* bp = src + (size_t)gy0 * 512 + gx0;
        for (int e = tid; e < 80 * 20; e += 256) {
            int rr = e / 20, g = e - rr * 20;
            *(float4*)&sx[rr * 84 + 4 * g] =
                *(const float4*)(bp + (size_t)rr * 512 + 4 * g);
        }
    } else {
        for (int e = tid; e < 80 * 80; e += 256) {
            int rr = e / 80, cc = e - rr * 80;
            int gr = refl(gy0 + rr, 512);
            int gc = refl(gx0 + cc, 512);
            sx[rr * 84 + cc] = src[(size_t)gr * 512 + gc];
        }
    }
    __syncthreads();

    // ---- row pass (rowdfilt) into registers ----
    const int jj  = tid & 31;
    const int odd = jj & 1;
    const int base = 2 * (jj & ~1);
    float hlo[10], hhi[10];
#pragma unroll
    for (int t = 0; t < 10; ++t) {
        hlo[t] = odd ? fa0[t] : fb0[t];
        hhi[t] = odd ? fb1[t] : fa1[t];
    }
    const int offlo = base + odd;
    const int offhi = base + 1 - odd;
    float rlo[10], rhi[10];
#pragma unroll
    for (int k = 0; k < 10; ++k) {
        int rr = (tid >> 5) + 8 * k;
        const float* row = &sx[rr * 84];
        float lo = 0.f, hi = 0.f;
#pragma unroll
        for (int t = 0; t < 10; ++t) {
            lo += row[offlo + 2 * t] * hlo[t];
            hi += row[offhi + 2 * t] * hhi[t];
        }
        rlo[k] = lo; rhi[k] = hi;
    }
    __syncthreads();
#pragma unroll
    for (int k = 0; k < 10; ++k) {
        int rr = (tid >> 5) + 8 * k;
        sloP[rr * 33 + jj] = rlo[k];
        shiP[rr * 33 + jj] = rhi[k];
    }
    __syncthreads();

    // ---- col pass: thread = (col j 0..31, rowgroup g 0..7) -> quad rows 2g,2g+1
    // loads 24+24 rows once (bank = row+col -> conflict-free), slides in regs,
    // q2c across the column-pair lanes via shfl_xor(1).
    const int j = tid & 31;
    const int g = tid >> 5;

    float clo[24], chi[24];
#pragma unroll
    for (int t = 0; t < 24; ++t) {
        clo[t] = sloP[(8 * g + t) * 33 + j];
        chi[t] = shiP[(8 * g + t) * 33 + j];
    }

    const int dj  = j & 1;
    const int qx  = (c0 >> 1) + (j >> 1);
    const int qy0 = (r0 >> 1) + 2 * g;
    const int oLH = dj ? 5 : 0;
    const int oHH = dj ? 4 : 1;
    const int oHL = dj ? 3 : 2;

    float* Zb = Z + (size_t)b * 147 * 16384 + (size_t)qy0 * 128 + qx;
    float* zLH = Zb + (size_t)((7 + oLH) * 3 + c) * 16384;
    float* zHH = Zb + (size_t)((7 + oHH) * 3 + c) * 16384;
    float* zHL = Zb + (size_t)((7 + oHL) * 3 + c) * 16384;
    float* zPL = Zb + (size_t)c * 16384;

#pragma unroll
    for (int r = 0; r < 2; ++r) {
        const int off = 4 * r;
        float vll0 = 0.f, vll1 = 0.f, vlh0 = 0.f, vlh1 = 0.f;
        float vhl0 = 0.f, vhl1 = 0.f, vhh0 = 0.f, vhh1 = 0.f;
#pragma unroll
        for (int t = 0; t < 10; ++t) {
            float e0 = clo[off + 2 * t];
            float e1 = clo[off + 2 * t + 1];
            float g0 = chi[off + 2 * t];
            float g1 = chi[off + 2 * t + 1];
            vll0 += e0 * fb0[t];
            vll1 += e1 * fa0[t];
            vlh0 += e1 * fa1[t];
            vlh1 += e0 * fb1[t];
            vhl0 += g0 * fb0[t];
            vhl1 += g1 * fa0[t];
            vhh0 += g1 * fa1[t];
            vhh1 += g0 * fb1[t];
        }

        // q2c: even lane holds (a,c) of the quad, odd holds (b,d)
        float lhT = __shfl_xor(vlh0, 1), lhB = __shfl_xor(vlh1, 1);
        float hhT = __shfl_xor(vhh0, 1), hhB = __shfl_xor(vhh1, 1);
        float hlT = __shfl_xor(vhl0, 1), hlB = __shfl_xor(vhl1, 1);
        float mLH = smag(IS2 * (vlh0 - lhB), IS2 * (lhT + vlh1));
        float mHH = smag(IS2 * (vhh0 - hhB), IS2 * (hhT + vhh1));
        float mHL = smag(IS2 * (vhl0 - hlB), IS2 * (hlT + vhl1));

        __builtin_nontemporal_store(mLH, zLH + r * 128);
        __builtin_nontemporal_store(mHH, zHH + r * 128);
        __builtin_nontemporal_store(mHL, zHL + r * 128);

        float llT = __shfl_xor(vll0, 1), llB = __shfl_xor(vll1, 1);
        if (dj == 0) {
            __builtin_nontemporal_store(
                0.25f * (vll0 + vll1 + llT + llB), zPL + r * 128);
        }
    }
}

// ---------------------------------------------------------------------------
// Kernel A: level-1 j1 on x -> ll + p
// ---------------------------------------------------------------------------
__global__ __launch_bounds__(256, 4)
void k_j1_l1(const float* __restrict__ x,
             const float* __restrict__ h0o, const float* __restrict__ h1o,
             float* __restrict__ ll, float* __restrict__ p)
{
    __shared__ __align__(16) float smem[9520];
    j1_tile<0, 512, 3>(smem, x, h0o, h1o, ll, p,
                       blockIdx.z, blockIdx.y * 64, blockIdx.x * 64);
}

// ---------------------------------------------------------------------------
// Kernel B: fused phase 2+3 (independent consumers of kernel A's outputs).
// blocks [0,6144): j2 tiles; [6144,15360): j1<1> tiles.
// ---------------------------------------------------------------------------
__global__ __launch_bounds__(256, 4)
void k_p23(const float* __restrict__ ll, const float* __restrict__ p,
           const float* __restrict__ h0o, const float* __restrict__ h1o,
           const float* __restrict__ h0a, const float* __restrict__ h0b,
           const float* __restrict__ h1a, const float* __restrict__ h1b,
           float* __restrict__ Z)
{
    __shared__ __align__(16) float smem[9520];
    const int B = blockIdx.x;
    if (B < 6144) {
        const int img = B >> 6, rem = B & 63;
        j2_tile(smem, ll, h0a, h0b, h1a, h1b, Z,
                img, ((rem >> 3) & 7) * 32, (rem & 7) * 32);
    } else {
        const int T = B - 6144;
        const int img = T >> 4, rem = T & 15;
        j1_tile<1, 256, 18>(smem, p, h0o, h1o, nullptr, Z,
                            img, ((rem >> 2) & 3) * 64, (rem & 3) * 64);
    }
}

extern "C" void kernel_launch(void* const* d_in, const int* in_sizes, int n_in,
                              void* d_out, int out_size, void* d_ws, size_t ws_size,
                              hipStream_t stream)
{
    const float* x   = (const float*)d_in[0];
    const float* h0o = (const float*)d_in[1];
    const float* h1o = (const float*)d_in[2];
    const float* h0a = (const float*)d_in[3];
    const float* h0b = (const float*)d_in[4];
    const float* h1a = (const float*)d_in[5];
    const float* h1b = (const float*)d_in[6];
    float* Z = (float*)d_out;

    float* ws_ll = (float*)d_ws;                          // (32,3,512,512)
    float* ws_p  = ws_ll + (size_t)32 * 3 * 512 * 512;    // (32,18,256,256)

    dim3 blk(256);
    // phase 1: level-1 j1 on x -> ll + p
    k_j1_l1<<<dim3(8, 8, 96), blk, 0, stream>>>(x, h0o, h1o, ws_ll, ws_p);
    // phases 2+3 fused: j2 on ll -> Z[s0,s1_j2]; j1<1> on p -> Z[s1_j1,s2]
    k_p23<<<dim3(15360), blk, 0, stream>>>(ws_ll, ws_p, h0o, h1o,
                                           h0a, h0b, h1a, h1b, Z);
}

// Round 4
// 559.377 us; speedup vs baseline: 1.1314x; 1.0048x over previous
//
#include <hip/hip_runtime.h>

typedef float v2f __attribute__((ext_vector_type(2)));

#define IS2 0.70710678118654752440f   // np.float32(1/sqrt(2))

__device__ __forceinline__ int refl(int i, int n) {
    if (i < 0) i = -1 - i;
    if (i >= n) i = 2 * n - 1 - i;
    return i;
}

__device__ __forceinline__ float smag(float re, float im) {
    return sqrtf(re * re + im * im + 1.0e-4f) - 0.01f;
}

// ---------------------------------------------------------------------------
// j1 tile: rowfilter(h0/h1) -> colfilter(h0/h1) -> q2c -> mag
// MODE 0: level-1 on x (N=512, CH=3): ll raw -> ll_out, mags -> p buffer
// MODE 1: level-2 on p (N=256, CH=18): mags -> Z groups 13+o2*6+o1 (NT),
//         avgpool2(ll) -> Z groups 1+o1 (NT).
// v4: row-pass output stored INTERLEAVED (lo,hi) pairs in LDS (70x128 region
// overlaying the 70x72 input tile). Col pass reads 22 ds_read_b64 (was 44 b32)
// and accumulates with packed-f32 math (v2f -> v_pk_fma_f32): lo and hi plane
// share every tap index and coefficient, so one pk-FMA does both planes.
// smem union: max(70*72, 70*128) = 8960 floats = 35.8 KB -> 4 blocks/CU.
// ---------------------------------------------------------------------------
template <int MODE, int N, int CH>
__device__ __forceinline__
void j1_tile(float* __restrict__ smem,
             const float* __restrict__ in,
             const float* __restrict__ h0,
             const float* __restrict__ h1,
             float* __restrict__ ll_out,
             float* __restrict__ mag_out,
             int img, int ty0, int tx0)
{
    const int b   = img / CH;
    const int chn = img % CH;
    const int tid = threadIdx.x;

    float* const sx = smem;   // 70*72 input tile (rows ty0-3.., cols tx0-4..)
    float* const s2 = smem;   // 70*128 interleaved (lo,hi) after row pass

    float f0[5], f1[7];
#pragma unroll
    for (int t = 0; t < 5; ++t) f0[t] = h0[t];
#pragma unroll
    for (int t = 0; t < 7; ++t) f1[t] = h1[t];

    const float* src = in + (size_t)img * N * N;

    // ---- load input tile: rows ty0-3..ty0+66, cols tx0-4..tx0+67 ----
    const bool interior = (ty0 >= 3) && (ty0 + 66 <= N - 1) &&
                          (tx0 >= 4) && (tx0 + 67 <= N - 1);
    if (interior) {
        const float* bp = src + (size_t)(ty0 - 3) * N + (tx0 - 4);
        for (int e = tid; e < 70 * 18; e += 256) {
            int rr = e / 18, g = e - rr * 18;
            *(float4*)&sx[rr * 72 + 4 * g] =
                *(const float4*)(bp + (size_t)rr * N + 4 * g);
        }
    } else {
        for (int e = tid; e < 70 * 72; e += 256) {
            int rr = e / 72, cc = e - rr * 72;
            int gr = refl(ty0 - 3 + rr, N);
            int gc = refl(tx0 - 4 + cc, N);
            sx[rr * 72 + cc] = src[(size_t)gr * N + gc];
        }
    }
    __syncthreads();

    // ---- row pass: 70 rows x 16 col-groups of 4; 3x b128 reads per group ----
    // output col jo=4g+u: lo taps sx cols jo+2..jo+6, hi taps jo+1..jo+7.
    float4 rA[5], rB[5];
#pragma unroll
    for (int k = 0; k < 5; ++k) {
        int e = tid + k * 256;
        if (e < 1120) {
            int rr = e >> 4, g = e & 15;
            const float4* w4 = (const float4*)&sx[rr * 72 + 4 * g];
            float4 wa = w4[0], wb = w4[1], wc = w4[2];
            float win[12] = {wa.x, wa.y, wa.z, wa.w,
                             wb.x, wb.y, wb.z, wb.w,
                             wc.x, wc.y, wc.z, wc.w};
            float lo[4], hi[4];
#pragma unroll
            for (int u = 0; u < 4; ++u) {
                float l = 0.f, h = 0.f;
#pragma unroll
                for (int t = 0; t < 5; ++t) l += win[u + 2 + t] * f0[t];
#pragma unroll
                for (int t = 0; t < 7; ++t) h += win[u + 1 + t] * f1[t];
                lo[u] = l; hi[u] = h;
            }
            rA[k] = make_float4(lo[0], hi[0], lo[1], hi[1]);
            rB[k] = make_float4(lo[2], hi[2], lo[3], hi[3]);
        }
    }
    __syncthreads();   // all reads of sx complete
#pragma unroll
    for (int k = 0; k < 5; ++k) {
        int e = tid + k * 256;
        if (e < 1120) {
            int rr = e >> 4, g = e & 15;
            *(float4*)&s2[rr * 128 + 8 * g]     = rA[k];
            *(float4*)&s2[rr * 128 + 8 * g + 4] = rB[k];
        }
    }
    __syncthreads();

    // ---- col pass: one column x 16-row strip per thread, packed lo/hi ----
    const int j     = tid & 63;    // output column
    const int rg    = tid >> 6;    // row-group 0..3
    const int rbase = rg * 16;

    v2f w[22];
#pragma unroll
    for (int t = 0; t < 22; ++t) {
        w[t] = *(const v2f*)&s2[(rbase + t) * 128 + 2 * j];
    }

    v2f f0d[5], f1d[7];
#pragma unroll
    for (int t = 0; t < 5; ++t) f0d[t] = (v2f){f0[t], f0[t]};
#pragma unroll
    for (int t = 0; t < 7; ++t) f1d[t] = (v2f){f1[t], f1[t]};

    const int Nh  = N >> 1;
    const int par = j & 1;
    const int qx  = (tx0 >> 1) + (j >> 1);
    const int qy0 = (ty0 >> 1) + rg * 8;
    const int oLH = par ? 5 : 0;
    const int oHH = par ? 4 : 1;
    const int oHL = par ? 3 : 2;

    float* lcol = nullptr;
    float* pLH = nullptr; float* pHH = nullptr; float* pHL = nullptr;
    float* zLH = nullptr; float* zHH = nullptr; float* zHL = nullptr;
    float* zPL = nullptr;
    if (MODE == 0) {
        lcol = ll_out + (size_t)img * N * N + (size_t)(ty0 + rbase) * N + tx0 + j;
        const size_t planeSz = (size_t)Nh * Nh;
        const size_t qoff = (size_t)qy0 * Nh + qx;
        pLH = mag_out + ((size_t)(b * 6 + oLH) * CH + chn) * planeSz + qoff;
        pHH = mag_out + ((size_t)(b * 6 + oHH) * CH + chn) * planeSz + qoff;
        pHL = mag_out + ((size_t)(b * 6 + oHL) * CH + chn) * planeSz + qoff;
    } else {
        const int o1 = chn / 3, c3 = chn % 3;
        float* zBase = mag_out + (size_t)b * 147 * 16384 + (size_t)qy0 * 128 + qx;
        zLH = zBase + (size_t)((13 + oLH * 6 + o1) * 3 + c3) * 16384;
        zHH = zBase + (size_t)((13 + oHH * 6 + o1) * 3 + c3) * 16384;
        zHL = zBase + (size_t)((13 + oHL * 6 + o1) * 3 + c3) * 16384;
        zPL = zBase + (size_t)((1 + o1) * 3 + c3) * 16384;
    }

#pragma unroll
    for (int ii = 0; ii < 8; ++ii) {
        const int i0 = 2 * ii, i1 = 2 * ii + 1;
        v2f A0 = {0.f, 0.f}, A1 = {0.f, 0.f};   // (ll, hl) rows i0, i1
        v2f C0 = {0.f, 0.f}, C1 = {0.f, 0.f};   // (lh, hh) rows i0, i1
#pragma unroll
        for (int t = 0; t < 5; ++t) {
            A0 += w[i0 + 1 + t] * f0d[t];
            A1 += w[i1 + 1 + t] * f0d[t];
        }
#pragma unroll
        for (int t = 0; t < 7; ++t) {
            C0 += w[i0 + t] * f1d[t];
            C1 += w[i1 + t] * f1d[t];
        }
        float ll0 = A0.x, hl0 = A0.y, ll1 = A1.x, hl1 = A1.y;
        float lh0 = C0.x, hh0 = C0.y, lh1 = C1.x, hh1 = C1.y;

        // q2c across the lane pair (even: a,c | odd: b,d); smag symmetric.
        float lhT = __shfl_xor(lh0, 1), lhB = __shfl_xor(lh1, 1);
        float hhT = __shfl_xor(hh0, 1), hhB = __shfl_xor(hh1, 1);
        float hlT = __shfl_xor(hl0, 1), hlB = __shfl_xor(hl1, 1);
        float mLH = smag(IS2 * (lh0 - lhB), IS2 * (lhT + lh1));
        float mHH = smag(IS2 * (hh0 - hhB), IS2 * (hhT + hh1));
        float mHL = smag(IS2 * (hl0 - hlB), IS2 * (hlT + hl1));

        if (MODE == 0) {
            lcol[(size_t)i0 * N] = ll0;
            lcol[(size_t)i1 * N] = ll1;
            pLH[ii * Nh] = mLH;
            pHH[ii * Nh] = mHH;
            pHL[ii * Nh] = mHL;
        } else {
            __builtin_nontemporal_store(mLH, zLH + ii * 128);
            __builtin_nontemporal_store(mHH, zHH + ii * 128);
            __builtin_nontemporal_store(mHL, zHL + ii * 128);
            float llT = __shfl_xor(ll0, 1), llB = __shfl_xor(ll1, 1);
            if (par == 0) {
                __builtin_nontemporal_store(
                    0.25f * (ll0 + ll1 + llT + llB), zPL + ii * 128);
            }
        }
    }
}

// ---------------------------------------------------------------------------
// j2 tile: rowdfilt -> coldfilt -> q2c -> mag -> Z[s1_j2] (NT), avgpool -> Z[s0] (NT)
// v4: row pass reads the stride-2 taps as aligned b64 PAIRS (both parities of
// a column pair read the SAME pair -> broadcast, conflict-free) and uses one
// pk-FMA per tap via a parity-pre-swapped filter pair (100 pk vs 200 FMA,
// 100 b64 vs 200 b32). Output stored interleaved (lo,hi); col pass loads 24
// b64 pairs (was 48 b32), scalar FMA (pk there would blow VGPR budget).
// smem union: max(80*84, 80*64) = 6720 floats.
// ---------------------------------------------------------------------------
__device__ __forceinline__
void j2_tile(float* __restrict__ smem,
             const float* __restrict__ ll,
             const float* __restrict__ h0a, const float* __restrict__ h0b,
             const float* __restrict__ h1a, const float* __restrict__ h1b,
             float* __restrict__ Z, int img, int r0, int c0)
{
    const int b = img / 3, c = img % 3;
    const int tid = threadIdx.x;

    float* const sx = smem;   // 80*84 input tile
    float* const s2 = smem;   // 80*64 interleaved (lo,hi) after row pass

    float fa0[10], fb0[10], fa1[10], fb1[10];
#pragma unroll
    for (int t = 0; t < 10; ++t) {
        fa0[t] = h0a[t]; fb0[t] = h0b[t];
        fa1[t] = h1a[t]; fb1[t] = h1b[t];
    }

    const float* src = ll + (size_t)img * 512 * 512;
    const int gy0 = 2 * r0 - 8, gx0 = 2 * c0 - 8;

    // ---- load 80x80 x-tile (rows/cols gy0..gy0+79), reflect at borders ----
    const bool interior = (gy0 >= 0) && (gy0 + 79 <= 511) &&
                          (gx0 >= 0) && (gx0 + 79 <= 511);
    if (interior) {
        const float* bp = src + (size_t)gy0 * 512 + gx0;
        for (int e = tid; e < 80 * 20; e += 256) {
            int rr = e / 20, g = e - rr * 20;
            *(float4*)&sx[rr * 84 + 4 * g] =
                *(const float4*)(bp + (size_t)rr * 512 + 4 * g);
        }
    } else {
        for (int e = tid; e < 80 * 80; e += 256) {
            int rr = e / 80, cc = e - rr * 80;
            int gr = refl(gy0 + rr, 512);
            int gc = refl(gx0 + cc, 512);
            sx[rr * 84 + cc] = src[(size_t)gr * 512 + gc];
        }
    }
    __syncthreads();

    // ---- row pass (rowdfilt), packed: acc = sum pair(row, base+2t) * fp[t]
    // even thread (odd=0): acc = (lo, hi); odd thread: acc = (hi, lo).
    const int jj  = tid & 31;
    const int odd = jj & 1;
    const int base = 2 * (jj & ~1);
    v2f fp[10];
#pragma unroll
    for (int t = 0; t < 10; ++t) {
        fp[t] = odd ? (v2f){fb1[t], fa0[t]} : (v2f){fb0[t], fa1[t]};
    }
    v2f racc[10];
#pragma unroll
    for (int k = 0; k < 10; ++k) {
        int rr = (tid >> 5) + 8 * k;
        const float* row = &sx[rr * 84 + base];
        v2f acc = {0.f, 0.f};
#pragma unroll
        for (int t = 0; t < 10; ++t) {
            acc += (*(const v2f*)&row[2 * t]) * fp[t];
        }
        racc[k] = odd ? (v2f){acc.y, acc.x} : acc;   // (lo, hi)
    }
    __syncthreads();   // all reads of sx complete
#pragma unroll
    for (int k = 0; k < 10; ++k) {
        int rr = (tid >> 5) + 8 * k;
        *(v2f*)&s2[rr * 64 + 2 * jj] = racc[k];
    }
    __syncthreads();

    // ---- col pass: thread = (col j 0..31, rowgroup g 0..7) -> quad rows 2g,2g+1
    const int j = tid & 31;
    const int g = tid >> 5;

    v2f w[24];
#pragma unroll
    for (int t = 0; t < 24; ++t) {
        w[t] = *(const v2f*)&s2[(8 * g + t) * 64 + 2 * j];
    }

    const int dj  = j & 1;
    const int qx  = (c0 >> 1) + (j >> 1);
    const int qy0 = (r0 >> 1) + 2 * g;
    const int oLH = dj ? 5 : 0;
    const int oHH = dj ? 4 : 1;
    const int oHL = dj ? 3 : 2;

    float* Zb = Z + (size_t)b * 147 * 16384 + (size_t)qy0 * 128 + qx;
    float* zLH = Zb + (size_t)((7 + oLH) * 3 + c) * 16384;
    float* zHH = Zb + (size_t)((7 + oHH) * 3 + c) * 16384;
    float* zHL = Zb + (size_t)((7 + oHL) * 3 + c) * 16384;
    float* zPL = Zb + (size_t)c * 16384;

#pragma unroll
    for (int r = 0; r < 2; ++r) {
        const int off = 4 * r;
        float vll0 = 0.f, vll1 = 0.f, vlh0 = 0.f, vlh1 = 0.f;
        float vhl0 = 0.f, vhl1 = 0.f, vhh0 = 0.f, vhh1 = 0.f;
#pragma unroll
        for (int t = 0; t < 10; ++t) {
            v2f p0 = w[off + 2 * t];       // (lo, hi) row off+2t
            v2f p1 = w[off + 2 * t + 1];   // (lo, hi) row off+2t+1
            vll0 += p0.x * fb0[t];
            vll1 += p1.x * fa0[t];
            vlh0 += p1.x * fa1[t];
            vlh1 += p0.x * fb1[t];
            vhl0 += p0.y * fb0[t];
            vhl1 += p1.y * fa0[t];
            vhh0 += p1.y * fa1[t];
            vhh1 += p0.y * fb1[t];
        }

        // q2c: even lane holds (a,c) of the quad, odd holds (b,d)
        float lhT = __shfl_xor(vlh0, 1), lhB = __shfl_xor(vlh1, 1);
        float hhT = __shfl_xor(vhh0, 1), hhB = __shfl_xor(vhh1, 1);
        float hlT = __shfl_xor(vhl0, 1), hlB = __shfl_xor(vhl1, 1);
        float mLH = smag(IS2 * (vlh0 - lhB), IS2 * (lhT + vlh1));
        float mHH = smag(IS2 * (vhh0 - hhB), IS2 * (hhT + vhh1));
        float mHL = smag(IS2 * (vhl0 - hlB), IS2 * (hlT + vhl1));

        __builtin_nontemporal_store(mLH, zLH + r * 128);
        __builtin_nontemporal_store(mHH, zHH + r * 128);
        __builtin_nontemporal_store(mHL, zHL + r * 128);

        float llT = __shfl_xor(vll0, 1), llB = __shfl_xor(vll1, 1);
        if (dj == 0) {
            __builtin_nontemporal_store(
                0.25f * (vll0 + vll1 + llT + llB), zPL + r * 128);
        }
    }
}

// ---------------------------------------------------------------------------
// Kernel A: level-1 j1 on x -> ll + p
// ---------------------------------------------------------------------------
__global__ __launch_bounds__(256, 4)
void k_j1_l1(const float* __restrict__ x,
             const float* __restrict__ h0o, const float* __restrict__ h1o,
             float* __restrict__ ll, float* __restrict__ p)
{
    __shared__ __align__(16) float smem[8960];
    j1_tile<0, 512, 3>(smem, x, h0o, h1o, ll, p,
                       blockIdx.z, blockIdx.y * 64, blockIdx.x * 64);
}

// ---------------------------------------------------------------------------
// Kernel B: fused phase 2+3 (independent consumers of kernel A's outputs).
// blocks [0,6144): j2 tiles; [6144,15360): j1<1> tiles.
// ---------------------------------------------------------------------------
__global__ __launch_bounds__(256, 4)
void k_p23(const float* __restrict__ ll, const float* __restrict__ p,
           const float* __restrict__ h0o, const float* __restrict__ h1o,
           const float* __restrict__ h0a, const float* __restrict__ h0b,
           const float* __restrict__ h1a, const float* __restrict__ h1b,
           float* __restrict__ Z)
{
    __shared__ __align__(16) float smem[8960];
    const int B = blockIdx.x;
    if (B < 6144) {
        const int img = B >> 6, rem = B & 63;
        j2_tile(smem, ll, h0a, h0b, h1a, h1b, Z,
                img, ((rem >> 3) & 7) * 32, (rem & 7) * 32);
    } else {
        const int T = B - 6144;
        const int img = T >> 4, rem = T & 15;
        j1_tile<1, 256, 18>(smem, p, h0o, h1o, nullptr, Z,
                            img, ((rem >> 2) & 3) * 64, (rem & 3) * 64);
    }
}

extern "C" void kernel_launch(void* const* d_in, const int* in_sizes, int n_in,
                              void* d_out, int out_size, void* d_ws, size_t ws_size,
                              hipStream_t stream)
{
    const float* x   = (const float*)d_in[0];
    const float* h0o = (const float*)d_in[1];
    const float* h1o = (const float*)d_in[2];
    const float* h0a = (const float*)d_in[3];
    const float* h0b = (const float*)d_in[4];
    const float* h1a = (const float*)d_in[5];
    const float* h1b = (const float*)d_in[6];
    float* Z = (float*)d_out;

    float* ws_ll = (float*)d_ws;                          // (32,3,512,512)
    float* ws_p  = ws_ll + (size_t)32 * 3 * 512 * 512;    // (32,18,256,256)

    dim3 blk(256);
    // phase 1: level-1 j1 on x -> ll + p
    k_j1_l1<<<dim3(8, 8, 96), blk, 0, stream>>>(x, h0o, h1o, ws_ll, ws_p);
    // phases 2+3 fused: j2 on ll -> Z[s0,s1_j2]; j1<1> on p -> Z[s1_j1,s2]
    k_p23<<<dim3(15360), blk, 0, stream>>>(ws_ll, ws_p, h0o, h1o,
                                           h0a, h0b, h1a, h1b, Z);
}

// Round 5
// 556.031 us; speedup vs baseline: 1.1382x; 1.0060x over previous
//
#include <hip/hip_runtime.h>

typedef float v2f __attribute__((ext_vector_type(2)));

#define IS2 0.70710678118654752440f   // np.float32(1/sqrt(2))

__device__ __forceinline__ int refl(int i, int n) {
    if (i < 0) i = -1 - i;
    if (i >= n) i = 2 * n - 1 - i;
    return i;
}

__device__ __forceinline__ float smag(float re, float im) {
    return sqrtf(re * re + im * im + 1.0e-4f) - 0.01f;
}

// ---------------------------------------------------------------------------
// j1 tile: rowfilter(h0/h1) -> colfilter(h0/h1) -> q2c -> mag
// MODE 0: level-1 on x (N=512, CH=3): ll raw -> ll_out, mags -> p buffer
// MODE 1: level-2 on p (N=256, CH=18): mags -> Z groups 13+o2*6+o1 (NT),
//         avgpool2(ll) -> Z groups 1+o1 (NT).
// v5: row-pass output stored SPLIT-PLANE in LDS: lo plane at row*128+j,
// hi plane at row*128+64+j (was interleaved (lo,hi) at 2j). Col-pass strip
// load becomes bank = j mod 32 (2-way, free) instead of 4-way-conflicted
// ds_read_b64 at even banks; the lo/hi pair per tap is a ds_read2_b32.
// pk-FMA retained by assembling v2f{lo,hi} in registers.
// smem union: max(70*72, 70*128) = 8960 floats = 35.8 KB -> 4 blocks/CU.
// ---------------------------------------------------------------------------
template <int MODE, int N, int CH>
__device__ __forceinline__
void j1_tile(float* __restrict__ smem,
             const float* __restrict__ in,
             const float* __restrict__ h0,
             const float* __restrict__ h1,
             float* __restrict__ ll_out,
             float* __restrict__ mag_out,
             int img, int ty0, int tx0)
{
    const int b   = img / CH;
    const int chn = img % CH;
    const int tid = threadIdx.x;

    float* const sx = smem;   // 70*72 input tile (rows ty0-3.., cols tx0-4..)
    float* const s2 = smem;   // 70 rows x [lo:64 | hi:64] after row pass

    float f0[5], f1[7];
#pragma unroll
    for (int t = 0; t < 5; ++t) f0[t] = h0[t];
#pragma unroll
    for (int t = 0; t < 7; ++t) f1[t] = h1[t];

    const float* src = in + (size_t)img * N * N;

    // ---- load input tile: rows ty0-3..ty0+66, cols tx0-4..tx0+67 ----
    const bool interior = (ty0 >= 3) && (ty0 + 66 <= N - 1) &&
                          (tx0 >= 4) && (tx0 + 67 <= N - 1);
    if (interior) {
        const float* bp = src + (size_t)(ty0 - 3) * N + (tx0 - 4);
        for (int e = tid; e < 70 * 18; e += 256) {
            int rr = e / 18, g = e - rr * 18;
            *(float4*)&sx[rr * 72 + 4 * g] =
                *(const float4*)(bp + (size_t)rr * N + 4 * g);
        }
    } else {
        for (int e = tid; e < 70 * 72; e += 256) {
            int rr = e / 72, cc = e - rr * 72;
            int gr = refl(ty0 - 3 + rr, N);
            int gc = refl(tx0 - 4 + cc, N);
            sx[rr * 72 + cc] = src[(size_t)gr * N + gc];
        }
    }
    __syncthreads();

    // ---- row pass: 70 rows x 16 col-groups of 4; 3x b128 reads per group ----
    // output col jo=4g+u: lo taps sx cols jo+2..jo+6, hi taps jo+1..jo+7.
    float4 rLo[5], rHi[5];
#pragma unroll
    for (int k = 0; k < 5; ++k) {
        int e = tid + k * 256;
        if (e < 1120) {
            int rr = e >> 4, g = e & 15;
            const float4* w4 = (const float4*)&sx[rr * 72 + 4 * g];
            float4 wa = w4[0], wb = w4[1], wc = w4[2];
            float win[12] = {wa.x, wa.y, wa.z, wa.w,
                             wb.x, wb.y, wb.z, wb.w,
                             wc.x, wc.y, wc.z, wc.w};
            float lo[4], hi[4];
#pragma unroll
            for (int u = 0; u < 4; ++u) {
                float l = 0.f, h = 0.f;
#pragma unroll
                for (int t = 0; t < 5; ++t) l += win[u + 2 + t] * f0[t];
#pragma unroll
                for (int t = 0; t < 7; ++t) h += win[u + 1 + t] * f1[t];
                lo[u] = l; hi[u] = h;
            }
            rLo[k] = make_float4(lo[0], lo[1], lo[2], lo[3]);
            rHi[k] = make_float4(hi[0], hi[1], hi[2], hi[3]);
        }
    }
    __syncthreads();   // all reads of sx complete
#pragma unroll
    for (int k = 0; k < 5; ++k) {
        int e = tid + k * 256;
        if (e < 1120) {
            int rr = e >> 4, g = e & 15;
            *(float4*)&s2[rr * 128 + 4 * g]      = rLo[k];
            *(float4*)&s2[rr * 128 + 64 + 4 * g] = rHi[k];
        }
    }
    __syncthreads();

    // ---- col pass: one column x 16-row strip per thread, packed lo/hi ----
    const int j     = tid & 63;    // output column
    const int rg    = tid >> 6;    // row-group 0..3
    const int rbase = rg * 16;

    v2f w[22];
#pragma unroll
    for (int t = 0; t < 22; ++t) {
        const float* rp = &s2[(rbase + t) * 128 + j];
        w[t] = (v2f){rp[0], rp[64]};   // ds_read2_b32, bank = j mod 32
    }

    v2f f0d[5], f1d[7];
#pragma unroll
    for (int t = 0; t < 5; ++t) f0d[t] = (v2f){f0[t], f0[t]};
#pragma unroll
    for (int t = 0; t < 7; ++t) f1d[t] = (v2f){f1[t], f1[t]};

    const int Nh  = N >> 1;
    const int par = j & 1;
    const int qx  = (tx0 >> 1) + (j >> 1);
    const int qy0 = (ty0 >> 1) + rg * 8;
    const int oLH = par ? 5 : 0;
    const int oHH = par ? 4 : 1;
    const int oHL = par ? 3 : 2;

    float* lcol = nullptr;
    float* pLH = nullptr; float* pHH = nullptr; float* pHL = nullptr;
    float* zLH = nullptr; float* zHH = nullptr; float* zHL = nullptr;
    float* zPL = nullptr;
    if (MODE == 0) {
        lcol = ll_out + (size_t)img * N * N + (size_t)(ty0 + rbase) * N + tx0 + j;
        const size_t planeSz = (size_t)Nh * Nh;
        const size_t qoff = (size_t)qy0 * Nh + qx;
        pLH = mag_out + ((size_t)(b * 6 + oLH) * CH + chn) * planeSz + qoff;
        pHH = mag_out + ((size_t)(b * 6 + oHH) * CH + chn) * planeSz + qoff;
        pHL = mag_out + ((size_t)(b * 6 + oHL) * CH + chn) * planeSz + qoff;
    } else {
        const int o1 = chn / 3, c3 = chn % 3;
        float* zBase = mag_out + (size_t)b * 147 * 16384 + (size_t)qy0 * 128 + qx;
        zLH = zBase + (size_t)((13 + oLH * 6 + o1) * 3 + c3) * 16384;
        zHH = zBase + (size_t)((13 + oHH * 6 + o1) * 3 + c3) * 16384;
        zHL = zBase + (size_t)((13 + oHL * 6 + o1) * 3 + c3) * 16384;
        zPL = zBase + (size_t)((1 + o1) * 3 + c3) * 16384;
    }

#pragma unroll
    for (int ii = 0; ii < 8; ++ii) {
        const int i0 = 2 * ii, i1 = 2 * ii + 1;
        v2f A0 = {0.f, 0.f}, A1 = {0.f, 0.f};   // (ll, hl) rows i0, i1
        v2f C0 = {0.f, 0.f}, C1 = {0.f, 0.f};   // (lh, hh) rows i0, i1
#pragma unroll
        for (int t = 0; t < 5; ++t) {
            A0 += w[i0 + 1 + t] * f0d[t];
            A1 += w[i1 + 1 + t] * f0d[t];
        }
#pragma unroll
        for (int t = 0; t < 7; ++t) {
            C0 += w[i0 + t] * f1d[t];
            C1 += w[i1 + t] * f1d[t];
        }
        float ll0 = A0.x, hl0 = A0.y, ll1 = A1.x, hl1 = A1.y;
        float lh0 = C0.x, hh0 = C0.y, lh1 = C1.x, hh1 = C1.y;

        // q2c across the lane pair (even: a,c | odd: b,d); smag symmetric.
        float lhT = __shfl_xor(lh0, 1), lhB = __shfl_xor(lh1, 1);
        float hhT = __shfl_xor(hh0, 1), hhB = __shfl_xor(hh1, 1);
        float hlT = __shfl_xor(hl0, 1), hlB = __shfl_xor(hl1, 1);
        float mLH = smag(IS2 * (lh0 - lhB), IS2 * (lhT + lh1));
        float mHH = smag(IS2 * (hh0 - hhB), IS2 * (hhT + hh1));
        float mHL = smag(IS2 * (hl0 - hlB), IS2 * (hlT + hl1));

        if (MODE == 0) {
            lcol[(size_t)i0 * N] = ll0;
            lcol[(size_t)i1 * N] = ll1;
            pLH[ii * Nh] = mLH;
            pHH[ii * Nh] = mHH;
            pHL[ii * Nh] = mHL;
        } else {
            __builtin_nontemporal_store(mLH, zLH + ii * 128);
            __builtin_nontemporal_store(mHH, zHH + ii * 128);
            __builtin_nontemporal_store(mHL, zHL + ii * 128);
            float llT = __shfl_xor(ll0, 1), llB = __shfl_xor(ll1, 1);
            if (par == 0) {
                __builtin_nontemporal_store(
                    0.25f * (ll0 + ll1 + llT + llB), zPL + ii * 128);
            }
        }
    }
}

// ---------------------------------------------------------------------------
// j2 tile: rowdfilt -> coldfilt -> q2c -> mag -> Z[s1_j2] (NT), avgpool -> Z[s0] (NT)
// v5: row-pass output stored SPLIT-PLANE: lo at row*64+jj, hi at row*64+32+jj
// (was interleaved at 2jj). Row-pass writes: bank = jj mod 32 (free, was
// 4-way); col-pass strip loads: bank = j mod 32 (free, was 4-way b64).
// Row pass keeps the broadcast-pair b64 reads of sx + pk-FMA.
// smem union: max(80*84, 80*64) = 6720 floats.
// ---------------------------------------------------------------------------
__device__ __forceinline__
void j2_tile(float* __restrict__ smem,
             const float* __restrict__ ll,
             const float* __restrict__ h0a, const float* __restrict__ h0b,
             const float* __restrict__ h1a, const float* __restrict__ h1b,
             float* __restrict__ Z, int img, int r0, int c0)
{
    const int b = img / 3, c = img % 3;
    const int tid = threadIdx.x;

    float* const sx = smem;   // 80*84 input tile
    float* const s2 = smem;   // 80 rows x [lo:32 | hi:32] after row pass

    float fa0[10], fb0[10], fa1[10], fb1[10];
#pragma unroll
    for (int t = 0; t < 10; ++t) {
        fa0[t] = h0a[t]; fb0[t] = h0b[t];
        fa1[t] = h1a[t]; fb1[t] = h1b[t];
    }

    const float* src = ll + (size_t)img * 512 * 512;
    const int gy0 = 2 * r0 - 8, gx0 = 2 * c0 - 8;

    // ---- load 80x80 x-tile (rows/cols gy0..gy0+79), reflect at borders ----
    const bool interior = (gy0 >= 0) && (gy0 + 79 <= 511) &&
                          (gx0 >= 0) && (gx0 + 79 <= 511);
    if (interior) {
        const float* bp = src + (size_t)gy0 * 512 + gx0;
        for (int e = tid; e < 80 * 20; e += 256) {
            int rr = e / 20, g = e - rr * 20;
            *(float4*)&sx[rr * 84 + 4 * g] =
                *(const float4*)(bp + (size_t)rr * 512 + 4 * g);
        }
    } else {
        for (int e = tid; e < 80 * 80; e += 256) {
            int rr = e / 80, cc = e - rr * 80;
            int gr = refl(gy0 + rr, 512);
            int gc = refl(gx0 + cc, 512);
            sx[rr * 84 + cc] = src[(size_t)gr * 512 + gc];
        }
    }
    __syncthreads();

    // ---- row pass (rowdfilt), packed: acc = sum pair(row, base+2t) * fp[t]
    // even thread (odd=0): acc = (lo, hi); odd thread: acc = (hi, lo).
    const int jj  = tid & 31;
    const int odd = jj & 1;
    const int base = 2 * (jj & ~1);
    v2f fp[10];
#pragma unroll
    for (int t = 0; t < 10; ++t) {
        fp[t] = odd ? (v2f){fb1[t], fa0[t]} : (v2f){fb0[t], fa1[t]};
    }
    v2f racc[10];
#pragma unroll
    for (int k = 0; k < 10; ++k) {
        int rr = (tid >> 5) + 8 * k;
        const float* row = &sx[rr * 84 + base];
        v2f acc = {0.f, 0.f};
#pragma unroll
        for (int t = 0; t < 10; ++t) {
            acc += (*(const v2f*)&row[2 * t]) * fp[t];
        }
        racc[k] = odd ? (v2f){acc.y, acc.x} : acc;   // (lo, hi)
    }
    __syncthreads();   // all reads of sx complete
#pragma unroll
    for (int k = 0; k < 10; ++k) {
        int rr = (tid >> 5) + 8 * k;
        s2[rr * 64 + jj]      = racc[k].x;   // lo plane, bank = jj (free)
        s2[rr * 64 + 32 + jj] = racc[k].y;   // hi plane (ds_write2_b32 pair)
    }
    __syncthreads();

    // ---- col pass: thread = (col j 0..31, rowgroup g 0..7) -> quad rows 2g,2g+1
    const int j = tid & 31;
    const int g = tid >> 5;

    v2f w[24];
#pragma unroll
    for (int t = 0; t < 24; ++t) {
        const float* rp = &s2[(8 * g + t) * 64 + j];
        w[t] = (v2f){rp[0], rp[32]};   // ds_read2_b32, bank = j mod 32
    }

    const int dj  = j & 1;
    const int qx  = (c0 >> 1) + (j >> 1);
    const int qy0 = (r0 >> 1) + 2 * g;
    const int oLH = dj ? 5 : 0;
    const int oHH = dj ? 4 : 1;
    const int oHL = dj ? 3 : 2;

    float* Zb = Z + (size_t)b * 147 * 16384 + (size_t)qy0 * 128 + qx;
    float* zLH = Zb + (size_t)((7 + oLH) * 3 + c) * 16384;
    float* zHH = Zb + (size_t)((7 + oHH) * 3 + c) * 16384;
    float* zHL = Zb + (size_t)((7 + oHL) * 3 + c) * 16384;
    float* zPL = Zb + (size_t)c * 16384;

#pragma unroll
    for (int r = 0; r < 2; ++r) {
        const int off = 4 * r;
        float vll0 = 0.f, vll1 = 0.f, vlh0 = 0.f, vlh1 = 0.f;
        float vhl0 = 0.f, vhl1 = 0.f, vhh0 = 0.f, vhh1 = 0.f;
#pragma unroll
        for (int t = 0; t < 10; ++t) {
            v2f p0 = w[off + 2 * t];       // (lo, hi) row off+2t
            v2f p1 = w[off + 2 * t + 1];   // (lo, hi) row off+2t+1
            vll0 += p0.x * fb0[t];
            vll1 += p1.x * fa0[t];
            vlh0 += p1.x * fa1[t];
            vlh1 += p0.x * fb1[t];
            vhl0 += p0.y * fb0[t];
            vhl1 += p1.y * fa0[t];
            vhh0 += p1.y * fa1[t];
            vhh1 += p0.y * fb1[t];
        }

        // q2c: even lane holds (a,c) of the quad, odd holds (b,d)
        float lhT = __shfl_xor(vlh0, 1), lhB = __shfl_xor(vlh1, 1);
        float hhT = __shfl_xor(vhh0, 1), hhB = __shfl_xor(vhh1, 1);
        float hlT = __shfl_xor(vhl0, 1), hlB = __shfl_xor(vhl1, 1);
        float mLH = smag(IS2 * (vlh0 - lhB), IS2 * (lhT + vlh1));
        float mHH = smag(IS2 * (vhh0 - hhB), IS2 * (hhT + vhh1));
        float mHL = smag(IS2 * (vhl0 - hlB), IS2 * (hlT + vhl1));

        __builtin_nontemporal_store(mLH, zLH + r * 128);
        __builtin_nontemporal_store(mHH, zHH + r * 128);
        __builtin_nontemporal_store(mHL, zHL + r * 128);

        float llT = __shfl_xor(vll0, 1), llB = __shfl_xor(vll1, 1);
        if (dj == 0) {
            __builtin_nontemporal_store(
                0.25f * (vll0 + vll1 + llT + llB), zPL + r * 128);
        }
    }
}

// ---------------------------------------------------------------------------
// Kernel A: level-1 j1 on x -> ll + p
// ---------------------------------------------------------------------------
__global__ __launch_bounds__(256, 4)
void k_j1_l1(const float* __restrict__ x,
             const float* __restrict__ h0o, const float* __restrict__ h1o,
             float* __restrict__ ll, float* __restrict__ p)
{
    __shared__ __align__(16) float smem[8960];
    j1_tile<0, 512, 3>(smem, x, h0o, h1o, ll, p,
                       blockIdx.z, blockIdx.y * 64, blockIdx.x * 64);
}

// ---------------------------------------------------------------------------
// Kernel B: fused phase 2+3 (independent consumers of kernel A's outputs).
// blocks [0,9216): j1<1> tiles (larger population first -> better tail
// packing); [9216,15360): j2 tiles.
// ---------------------------------------------------------------------------
__global__ __launch_bounds__(256, 4)
void k_p23(const float* __restrict__ ll, const float* __restrict__ p,
           const float* __restrict__ h0o, const float* __restrict__ h1o,
           const float* __restrict__ h0a, const float* __restrict__ h0b,
           const float* __restrict__ h1a, const float* __restrict__ h1b,
           float* __restrict__ Z)
{
    __shared__ __align__(16) float smem[8960];
    const int B = blockIdx.x;
    if (B < 9216) {
        const int img = B >> 4, rem = B & 15;
        j1_tile<1, 256, 18>(smem, p, h0o, h1o, nullptr, Z,
                            img, ((rem >> 2) & 3) * 64, (rem & 3) * 64);
    } else {
        const int T = B - 9216;
        const int img = T >> 6, rem = T & 63;
        j2_tile(smem, ll, h0a, h0b, h1a, h1b, Z,
                img, ((rem >> 3) & 7) * 32, (rem & 7) * 32);
    }
}

extern "C" void kernel_launch(void* const* d_in, const int* in_sizes, int n_in,
                              void* d_out, int out_size, void* d_ws, size_t ws_size,
                              hipStream_t stream)
{
    const float* x   = (const float*)d_in[0];
    const float* h0o = (const float*)d_in[1];
    const float* h1o = (const float*)d_in[2];
    const float* h0a = (const float*)d_in[3];
    const float* h0b = (const float*)d_in[4];
    const float* h1a = (const float*)d_in[5];
    const float* h1b = (const float*)d_in[6];
    float* Z = (float*)d_out;

    float* ws_ll = (float*)d_ws;                          // (32,3,512,512)
    float* ws_p  = ws_ll + (size_t)32 * 3 * 512 * 512;    // (32,18,256,256)

    dim3 blk(256);
    // phase 1: level-1 j1 on x -> ll + p
    k_j1_l1<<<dim3(8, 8, 96), blk, 0, stream>>>(x, h0o, h1o, ws_ll, ws_p);
    // phases 2+3 fused: j1<1> on p -> Z[s1_j1,s2]; j2 on ll -> Z[s0,s1_j2]
    k_p23<<<dim3(15360), blk, 0, stream>>>(ws_ll, ws_p, h0o, h1o,
                                           h0a, h0b, h1a, h1b, Z);
}